// Round 1
// baseline (1430.395 us; speedup 1.0000x reference)
//
#include <hip/hip_runtime.h>
#include <math.h>

#define N_NODES 100000
#define N_EDGES 1600000
#define D_IN 512
#define C1 128   // H1*D1
#define H1 8
#define D2 64
#define SLOPE 0.2f

// ---------------- copy feats -> out0 ----------------
__global__ void k_copy_feats(const float4* __restrict__ src, float4* __restrict__ dst, int n4) {
    int i = blockIdx.x * blockDim.x + threadIdx.x;
    if (i < n4) dst[i] = src[i];
}

// ---------------- CSR build ----------------
__global__ void k_hist(const int* __restrict__ dst, int* __restrict__ cnt) {
    int e = blockIdx.x * blockDim.x + threadIdx.x;
    if (e < N_EDGES) atomicAdd(&cnt[dst[e]], 1);
}

// single-block chunked exclusive scan over N_NODES counts
__global__ void k_scan(const int* __restrict__ cnt, int* __restrict__ row_start,
                       int* __restrict__ cursor) {
    __shared__ int sdata[1024];
    int t = threadIdx.x;
    int running = 0;
    for (int base = 0; base < N_NODES; base += 1024) {
        int idx = base + t;
        int v = (idx < N_NODES) ? cnt[idx] : 0;
        sdata[t] = v;
        __syncthreads();
        for (int off = 1; off < 1024; off <<= 1) {
            int x = 0;
            if (t >= off) x = sdata[t - off];
            __syncthreads();
            sdata[t] += x;
            __syncthreads();
        }
        int incl = sdata[t];
        int excl = incl - v;
        if (idx < N_NODES) { row_start[idx] = running + excl; cursor[idx] = running + excl; }
        int total = sdata[1023];
        __syncthreads();
        running += total;
    }
    if (t == 0) row_start[N_NODES] = running;
}

__global__ void k_scatter(const int* __restrict__ src, const int* __restrict__ dst,
                          int* __restrict__ cursor, int* __restrict__ csr_src) {
    int e = blockIdx.x * blockDim.x + threadIdx.x;
    if (e < N_EDGES) {
        int pos = atomicAdd(&cursor[dst[e]], 1);
        csr_src[pos] = src[e];
    }
}

// ---------------- GEMM1: ft1[n][o] = sum_k feats[n][k]*W1[o][k] ----------------
// tile: 64 rows x 128 cols (all outputs) x BK=32, 256 threads, 4x8 micro-tile
__global__ __launch_bounds__(256) void k_gemm1(const float* __restrict__ feats,
                                               const float* __restrict__ W1,
                                               float* __restrict__ ft1) {
    __shared__ float As[64 * 33];    // [row][k], stride 33 (pad)
    __shared__ float Bs[32 * 132];   // [k][o], stride 132 (pad)
    int t = threadIdx.x;
    int tx = t & 15, ty = t >> 4;
    int m0 = blockIdx.x * 64;
    float acc[4][8];
#pragma unroll
    for (int i = 0; i < 4; i++)
#pragma unroll
        for (int j = 0; j < 8; j++) acc[i][j] = 0.f;

    for (int kt = 0; kt < D_IN; kt += 32) {
        // stage A: 64x32 = 512 float4
#pragma unroll
        for (int l = 0; l < 2; ++l) {
            int idx = t + l * 256;
            int row = idx >> 3, k4 = idx & 7;
            int n = m0 + row;
            float4 v = make_float4(0.f, 0.f, 0.f, 0.f);
            if (n < N_NODES) v = *(const float4*)(feats + n * D_IN + kt + k4 * 4);
            As[row * 33 + k4 * 4 + 0] = v.x;
            As[row * 33 + k4 * 4 + 1] = v.y;
            As[row * 33 + k4 * 4 + 2] = v.z;
            As[row * 33 + k4 * 4 + 3] = v.w;
        }
        // stage B transposed: W1[o][kt+kk] -> Bs[kk][o], 128x32 = 1024 float4
#pragma unroll
        for (int l = 0; l < 4; ++l) {
            int idx = t + l * 256;
            int o = idx >> 3, k4 = idx & 7;
            float4 v = *(const float4*)(W1 + o * D_IN + kt + k4 * 4);
            Bs[(k4 * 4 + 0) * 132 + o] = v.x;
            Bs[(k4 * 4 + 1) * 132 + o] = v.y;
            Bs[(k4 * 4 + 2) * 132 + o] = v.z;
            Bs[(k4 * 4 + 3) * 132 + o] = v.w;
        }
        __syncthreads();
#pragma unroll
        for (int kk = 0; kk < 32; ++kk) {
            float a[4], b[8];
#pragma unroll
            for (int i = 0; i < 4; i++) a[i] = As[(ty * 4 + i) * 33 + kk];
#pragma unroll
            for (int j = 0; j < 8; j++) b[j] = Bs[kk * 132 + tx * 8 + j];
#pragma unroll
            for (int i = 0; i < 4; i++)
#pragma unroll
                for (int j = 0; j < 8; j++) acc[i][j] = fmaf(a[i], b[j], acc[i][j]);
        }
        __syncthreads();
    }
#pragma unroll
    for (int i = 0; i < 4; i++) {
        int n = m0 + ty * 4 + i;
        if (n < N_NODES) {
            float4 v0 = make_float4(acc[i][0], acc[i][1], acc[i][2], acc[i][3]);
            float4 v1 = make_float4(acc[i][4], acc[i][5], acc[i][6], acc[i][7]);
            *(float4*)(ft1 + n * C1 + tx * 8) = v0;
            *(float4*)(ft1 + n * C1 + tx * 8 + 4) = v1;
        }
    }
}

// ---------------- el1/er1 per (node, head) ----------------
__global__ void k_eler1(const float* __restrict__ ft1, const float* __restrict__ al1,
                        const float* __restrict__ ar1, float* __restrict__ el1,
                        float* __restrict__ er1) {
    int g = blockIdx.x * blockDim.x + threadIdx.x;
    if (g >= N_NODES * H1) return;
    int n = g >> 3, h = g & 7;
    const float* f = ft1 + n * C1 + h * 16;
    const float* a = al1 + h * 16;
    const float* b = ar1 + h * 16;
    float sl = 0.f, sr = 0.f;
#pragma unroll
    for (int d = 0; d < 16; ++d) {
        float v = f[d];
        sl = fmaf(v, a[d], sl);
        sr = fmaf(v, b[d], sr);
    }
    el1[g] = sl;
    er1[g] = sr;
}

// ---------------- layer0 aggregation: one wave per dst node ----------------
__global__ __launch_bounds__(256) void k_agg1(const float* __restrict__ ft1,
                                              const float* __restrict__ el1,
                                              const float* __restrict__ er1,
                                              const int* __restrict__ row_start,
                                              const int* __restrict__ csr_src,
                                              float* __restrict__ h1out) {
    int lane = threadIdx.x & 63;
    int n = blockIdx.x * 4 + (threadIdx.x >> 6);
    if (n >= N_NODES) return;
    int ha = lane >> 4;      // head of element `lane`        (0..3)
    int hb = ha + 4;         // head of element `lane+64`     (4..7)
    float era = er1[n * 8 + ha];
    float erb = er1[n * 8 + hb];
    int beg = row_start[n], end = row_start[n + 1];
    float acc0 = 0.f, acc1 = 0.f, s0 = 0.f, s1 = 0.f;
    for (int i = beg; i < end; ++i) {
        int s = csr_src[i];
        float e0 = el1[s * 8 + ha] + era;
        float e1 = el1[s * 8 + hb] + erb;
        e0 = e0 >= 0.f ? e0 : SLOPE * e0;
        e1 = e1 >= 0.f ? e1 : SLOPE * e1;
        float w0 = __expf(e0);
        float w1 = __expf(e1);
        acc0 = fmaf(w0, ft1[s * C1 + lane], acc0);
        acc1 = fmaf(w1, ft1[s * C1 + 64 + lane], acc1);
        s0 += w0;
        s1 += w1;
    }
    float r0 = (s0 > 0.f) ? acc0 / s0 : 0.f;
    float r1 = (s1 > 0.f) ? acc1 / s1 : 0.f;
    h1out[n * C1 + lane] = fmaxf(r0, 0.f);       // relu
    h1out[n * C1 + 64 + lane] = fmaxf(r1, 0.f);
}

// ---------------- GEMM2 + el2/er2: ft2[n][o] = sum_k h1[n][k]*W2[o][k] ----------------
__global__ __launch_bounds__(256) void k_gemm2(const float* __restrict__ h1,
                                               const float* __restrict__ W2,
                                               const float* __restrict__ al2,
                                               const float* __restrict__ ar2,
                                               float* __restrict__ ft2,
                                               float* __restrict__ el2,
                                               float* __restrict__ er2) {
    __shared__ float W2t[128 * 65];  // [k][o], stride 65
    __shared__ float Hs[4 * 128];
    int t = threadIdx.x;
    int n0 = blockIdx.x * 4;
    // stage W2 transposed: 64x128 = 2048 float4
#pragma unroll
    for (int l = 0; l < 8; ++l) {
        int idx = t + l * 256;
        int o = idx >> 5, k4 = idx & 31;
        float4 v = *(const float4*)(W2 + o * C1 + k4 * 4);
        W2t[(k4 * 4 + 0) * 65 + o] = v.x;
        W2t[(k4 * 4 + 1) * 65 + o] = v.y;
        W2t[(k4 * 4 + 2) * 65 + o] = v.z;
        W2t[(k4 * 4 + 3) * 65 + o] = v.w;
    }
    // stage 4 h1 rows
    if (t < 128) {
        int ni = t >> 5, k4 = t & 31;
        int n = n0 + ni;
        float4 v = make_float4(0.f, 0.f, 0.f, 0.f);
        if (n < N_NODES) v = *(const float4*)(h1 + n * C1 + k4 * 4);
        *(float4*)(Hs + ni * C1 + k4 * 4) = v;
    }
    __syncthreads();
    int o = t & 63, ni = t >> 6;
    int n = n0 + ni;
    float acc = 0.f;
#pragma unroll 8
    for (int k = 0; k < C1; ++k) acc = fmaf(Hs[ni * C1 + k], W2t[k * 65 + o], acc);
    float p = acc * al2[o];
    float q = acc * ar2[o];
#pragma unroll
    for (int off = 32; off > 0; off >>= 1) {
        p += __shfl_down(p, off, 64);
        q += __shfl_down(q, off, 64);
    }
    if (n < N_NODES) {
        ft2[n * D2 + o] = acc;
        if (o == 0) { el2[n] = p; er2[n] = q; }
    }
}

// ---------------- layer1 aggregation: one wave per dst node ----------------
__global__ __launch_bounds__(256) void k_agg2(const float* __restrict__ ft2,
                                              const float* __restrict__ el2,
                                              const float* __restrict__ er2,
                                              const int* __restrict__ row_start,
                                              const int* __restrict__ csr_src,
                                              float* __restrict__ out2) {
    int lane = threadIdx.x & 63;
    int n = blockIdx.x * 4 + (threadIdx.x >> 6);
    if (n >= N_NODES) return;
    float ern = er2[n];
    int beg = row_start[n], end = row_start[n + 1];
    float acc = 0.f, ssum = 0.f;
    for (int i = beg; i < end; ++i) {
        int s = csr_src[i];
        float e = el2[s] + ern;
        e = e >= 0.f ? e : SLOPE * e;
        float w = __expf(e);
        acc = fmaf(w, ft2[s * D2 + lane], acc);
        ssum += w;
    }
    out2[n * D2 + lane] = (ssum > 0.f) ? acc / ssum : 0.f;
}

extern "C" void kernel_launch(void* const* d_in, const int* in_sizes, int n_in,
                              void* d_out, int out_size, void* d_ws, size_t ws_size,
                              hipStream_t stream) {
    const float* feats = (const float*)d_in[0];
    const int* src = (const int*)d_in[1];
    const int* dst = (const int*)d_in[2];
    const float* W1 = (const float*)d_in[3];
    const float* al1 = (const float*)d_in[4];
    const float* ar1 = (const float*)d_in[5];
    const float* W2 = (const float*)d_in[6];
    const float* al2 = (const float*)d_in[7];
    const float* ar2 = (const float*)d_in[8];

    float* out0 = (float*)d_out;                       // feats copy [N,512]
    float* out1 = out0 + (size_t)N_NODES * D_IN;       // h1 [N,128]
    float* out2 = out1 + (size_t)N_NODES * C1;         // h  [N,64]

    char* ws = (char*)d_ws;
    size_t off = 0;
    auto alloc = [&](size_t bytes) -> void* {
        void* p = ws + off;
        off = (off + bytes + 255) & ~(size_t)255;
        return p;
    };
    float* ft1 = (float*)alloc((size_t)N_NODES * C1 * 4);
    float* el1 = (float*)alloc((size_t)N_NODES * H1 * 4);
    float* er1 = (float*)alloc((size_t)N_NODES * H1 * 4);
    float* ft2 = (float*)alloc((size_t)N_NODES * D2 * 4);
    float* el2 = (float*)alloc((size_t)N_NODES * 4);
    float* er2 = (float*)alloc((size_t)N_NODES * 4);
    int* cnt = (int*)alloc((size_t)N_NODES * 4);
    int* row_start = (int*)alloc((size_t)(N_NODES + 1) * 4);
    int* cursor = (int*)alloc((size_t)N_NODES * 4);
    int* csr_src = (int*)alloc((size_t)N_EDGES * 4);

    // CSR build (shared by both layers)
    hipMemsetAsync(cnt, 0, (size_t)N_NODES * 4, stream);
    k_hist<<<(N_EDGES + 255) / 256, 256, 0, stream>>>(dst, cnt);
    k_scan<<<1, 1024, 0, stream>>>(cnt, row_start, cursor);
    k_scatter<<<(N_EDGES + 255) / 256, 256, 0, stream>>>(src, dst, cursor, csr_src);

    // out0 = feats
    int n4 = N_NODES * D_IN / 4;
    k_copy_feats<<<(n4 + 255) / 256, 256, 0, stream>>>((const float4*)feats, (float4*)out0, n4);

    // layer 0
    k_gemm1<<<(N_NODES + 63) / 64, 256, 0, stream>>>(feats, W1, ft1);
    k_eler1<<<(N_NODES * H1 + 255) / 256, 256, 0, stream>>>(ft1, al1, ar1, el1, er1);
    k_agg1<<<(N_NODES + 3) / 4, 256, 0, stream>>>(ft1, el1, er1, row_start, csr_src, out1);

    // layer 1
    k_gemm2<<<(N_NODES + 3) / 4, 256, 0, stream>>>(out1, W2, al2, ar2, ft2, el2, er2);
    k_agg2<<<(N_NODES + 3) / 4, 256, 0, stream>>>(ft2, el2, er2, row_start, csr_src, out2);
}

// Round 3
// 1031.916 us; speedup vs baseline: 1.3862x; 1.3862x over previous
//
#include <hip/hip_runtime.h>
#include <math.h>

#define N_NODES 100000
#define N_EDGES 1600000
#define D_IN 512
#define C1 128   // H1*D1
#define H1 8
#define D2 64
#define SLOPE 0.2f
#define NB_SCAN 98   // ceil(100000/1024)

typedef unsigned short u16;
typedef u16 u16x4 __attribute__((ext_vector_type(4)));
typedef u16 u16x8 __attribute__((ext_vector_type(8)));
typedef short bf16x8 __attribute__((ext_vector_type(8)));
typedef float f32x4 __attribute__((ext_vector_type(4)));

__device__ __forceinline__ u16 f2bf(float f) {
    unsigned u = __builtin_bit_cast(unsigned, f);
    u += 0x7fffu + ((u >> 16) & 1u);   // RNE
    return (u16)(u >> 16);
}
__device__ __forceinline__ float bf2f(u16 v) {
    unsigned u = ((unsigned)v) << 16;
    return __builtin_bit_cast(float, u);
}

// ---------------- copy feats -> out0 ----------------
__global__ void k_copy_feats(const float4* __restrict__ src, float4* __restrict__ dst, int n4) {
    int i = blockIdx.x * blockDim.x + threadIdx.x;
    if (i < n4) dst[i] = src[i];
}

// ---------------- CSR build ----------------
__global__ void k_hist(const int* __restrict__ dst, int* __restrict__ cnt) {
    int e = blockIdx.x * blockDim.x + threadIdx.x;
    if (e < N_EDGES) atomicAdd(&cnt[dst[e]], 1);
}

__global__ void k_scan_partials(const int* __restrict__ cnt, int* __restrict__ partials) {
    __shared__ int s[256];
    int t = threadIdx.x;
    int base = blockIdx.x * 1024 + t * 4;
    int sum = 0;
#pragma unroll
    for (int j = 0; j < 4; j++) { int i = base + j; if (i < N_NODES) sum += cnt[i]; }
    s[t] = sum;
    __syncthreads();
    for (int off = 128; off > 0; off >>= 1) {
        if (t < off) s[t] += s[t + off];
        __syncthreads();
    }
    if (t == 0) partials[blockIdx.x] = s[0];
}

__global__ void k_scan_offsets(const int* __restrict__ partials, int* __restrict__ offsets,
                               int* __restrict__ row_start) {
    int run = 0;
    for (int i = 0; i < NB_SCAN; i++) { offsets[i] = run; run += partials[i]; }
    row_start[N_NODES] = run;
}

__global__ void k_scan_final(const int* __restrict__ cnt, const int* __restrict__ offsets,
                             int* __restrict__ row_start, int* __restrict__ cursor) {
    __shared__ int s[256];
    int t = threadIdx.x;
    int base = blockIdx.x * 1024 + t * 4;
    int v[4];
    int sum = 0;
#pragma unroll
    for (int j = 0; j < 4; j++) {
        int i = base + j;
        v[j] = (i < N_NODES) ? cnt[i] : 0;
        sum += v[j];
    }
    s[t] = sum;
    __syncthreads();
    for (int off = 1; off < 256; off <<= 1) {
        int x = (t >= off) ? s[t - off] : 0;
        __syncthreads();
        s[t] += x;
        __syncthreads();
    }
    int b = offsets[blockIdx.x] + s[t] - sum;
    int e = 0;
#pragma unroll
    for (int j = 0; j < 4; j++) {
        int i = base + j;
        if (i < N_NODES) { row_start[i] = b + e; cursor[i] = b + e; }
        e += v[j];
    }
}

__global__ void k_scatter(const int* __restrict__ src, const int* __restrict__ dst,
                          int* __restrict__ cursor, int* __restrict__ csr_src) {
    int e = blockIdx.x * blockDim.x + threadIdx.x;
    if (e < N_EDGES) {
        int pos = atomicAdd(&cursor[dst[e]], 1);
        csr_src[pos] = src[e];
    }
}

// ---------------- GEMM1 (bf16 MFMA): ft1b[n][o] = sum_k feats[n][k]*W1[o][k] ----------------
// M_tile=64 (4 waves x 16 rows), N=128 (8 col-tiles of 16), BK=32
__global__ __launch_bounds__(256) void k_gemm1(const float* __restrict__ feats,
                                               const float* __restrict__ W1,
                                               u16* __restrict__ ft1b) {
    __shared__ u16 As[64 * 40];    // [row][k] stride 40 (16B-aligned rows, <=2-way banks)
    __shared__ u16 Bs[128 * 40];   // [o][k] stride 40
    int t = threadIdx.x;
    int m0 = blockIdx.x * 64;
    int wave = t >> 6, lane = t & 63, quad = lane >> 4, mr = lane & 15;

    f32x4 acc[8];
#pragma unroll
    for (int i = 0; i < 8; i++)
#pragma unroll
        for (int j = 0; j < 4; j++) acc[i][j] = 0.f;

    for (int kt = 0; kt < D_IN; kt += 32) {
        __syncthreads();
        // stage A: 64 rows x 32 k fp32 -> bf16 (512 float4, 2/thread)
#pragma unroll
        for (int l = 0; l < 2; ++l) {
            int idx = t + l * 256;
            int row = idx >> 3, k4 = idx & 7;
            int n = m0 + row;
            float4 v = make_float4(0.f, 0.f, 0.f, 0.f);
            if (n < N_NODES) v = *(const float4*)(feats + (size_t)n * D_IN + kt + k4 * 4);
            u16x4 b; b.x = f2bf(v.x); b.y = f2bf(v.y); b.z = f2bf(v.z); b.w = f2bf(v.w);
            *(u16x4*)(As + row * 40 + k4 * 4) = b;
        }
        // stage B: 128 rows x 32 k (1024 float4, 4/thread)
#pragma unroll
        for (int l = 0; l < 4; ++l) {
            int idx = t + l * 256;
            int o = idx >> 3, k4 = idx & 7;
            float4 v = *(const float4*)(W1 + (size_t)o * D_IN + kt + k4 * 4);
            u16x4 b; b.x = f2bf(v.x); b.y = f2bf(v.y); b.z = f2bf(v.z); b.w = f2bf(v.w);
            *(u16x4*)(Bs + o * 40 + k4 * 4) = b;
        }
        __syncthreads();
        bf16x8 a = *(const bf16x8*)(As + (wave * 16 + mr) * 40 + quad * 8);
#pragma unroll
        for (int nt = 0; nt < 8; ++nt) {
            bf16x8 b = *(const bf16x8*)(Bs + (nt * 16 + mr) * 40 + quad * 8);
            acc[nt] = __builtin_amdgcn_mfma_f32_16x16x32_bf16(a, b, acc[nt], 0, 0, 0);
        }
    }
    // epilogue: C/D layout col=lane&15, row=quad*4+reg
#pragma unroll
    for (int nt = 0; nt < 8; ++nt)
#pragma unroll
        for (int r = 0; r < 4; ++r) {
            int n = m0 + wave * 16 + quad * 4 + r;
            if (n < N_NODES) ft1b[(size_t)n * C1 + nt * 16 + mr] = f2bf(acc[nt][r]);
        }
}

// ---------------- el1/er1 per (node, head) ----------------
__global__ void k_eler1(const u16* __restrict__ ft1b, const float* __restrict__ al1,
                        const float* __restrict__ ar1, float* __restrict__ el1,
                        float* __restrict__ er1) {
    int g = blockIdx.x * blockDim.x + threadIdx.x;
    if (g >= N_NODES * H1) return;
    int n = g >> 3, h = g & 7;
    const u16* f = ft1b + (size_t)n * C1 + h * 16;
    float sl = 0.f, sr = 0.f;
#pragma unroll
    for (int d = 0; d < 16; ++d) {
        float v = bf2f(f[d]);
        sl = fmaf(v, al1[h * 16 + d], sl);
        sr = fmaf(v, ar1[h * 16 + d], sr);
    }
    el1[g] = sl;
    er1[g] = sr;
}

// ---------------- layer0 aggregation: one wave per dst node ----------------
__global__ __launch_bounds__(256) void k_agg1(const u16* __restrict__ ft1b,
                                              const float* __restrict__ el1,
                                              const float* __restrict__ er1,
                                              const int* __restrict__ row_start,
                                              const int* __restrict__ csr_src,
                                              float* __restrict__ h1out,
                                              u16* __restrict__ h1b) {
    int lane = threadIdx.x & 63;
    int n = blockIdx.x * 4 + (threadIdx.x >> 6);
    if (n >= N_NODES) return;
    int ha = lane >> 4;      // head of element `lane`        (0..3)
    int hb = ha + 4;         // head of element `lane+64`     (4..7)
    float era = er1[n * 8 + ha];
    float erb = er1[n * 8 + hb];
    int beg = row_start[n], end = row_start[n + 1];
    float acc0 = 0.f, acc1 = 0.f, s0 = 0.f, s1 = 0.f;
    for (int i = beg; i < end; ++i) {
        int s = csr_src[i];
        float e0 = el1[s * 8 + ha] + era;
        float e1 = el1[s * 8 + hb] + erb;
        e0 = e0 >= 0.f ? e0 : SLOPE * e0;
        e1 = e1 >= 0.f ? e1 : SLOPE * e1;
        float w0 = __expf(e0);
        float w1 = __expf(e1);
        acc0 = fmaf(w0, bf2f(ft1b[(size_t)s * C1 + lane]), acc0);
        acc1 = fmaf(w1, bf2f(ft1b[(size_t)s * C1 + 64 + lane]), acc1);
        s0 += w0;
        s1 += w1;
    }
    float r0 = (s0 > 0.f) ? fmaxf(acc0 / s0, 0.f) : 0.f;   // relu
    float r1 = (s1 > 0.f) ? fmaxf(acc1 / s1, 0.f) : 0.f;
    h1out[(size_t)n * C1 + lane] = r0;
    h1out[(size_t)n * C1 + 64 + lane] = r1;
    h1b[(size_t)n * C1 + lane] = f2bf(r0);
    h1b[(size_t)n * C1 + 64 + lane] = f2bf(r1);
}

// ---------------- GEMM2 (bf16 MFMA): ft2b[n][o] = sum_k h1[n][k]*W2[o][k] ----------------
// 128 nodes/block, N=64 (4 col-tiles), K=128 staged once
__global__ __launch_bounds__(256) void k_gemm2(const u16* __restrict__ h1b,
                                               const float* __restrict__ W2,
                                               u16* __restrict__ ft2b) {
    __shared__ u16 As[128 * 136];
    __shared__ u16 Bs[64 * 136];
    int t = threadIdx.x;
    int n0 = blockIdx.x * 128;
    // stage A: 128 rows x 128 bf16 = 2048 x 16B chunks, 8/thread
#pragma unroll
    for (int l = 0; l < 8; ++l) {
        int idx = t + l * 256;
        int row = idx >> 4, c8 = idx & 15;
        int n = n0 + row;
        u16x8 v;
#pragma unroll
        for (int j = 0; j < 8; j++) v[j] = 0;
        if (n < N_NODES) v = *(const u16x8*)(h1b + (size_t)n * C1 + c8 * 8);
        *(u16x8*)(As + row * 136 + c8 * 8) = v;
    }
    // stage B: W2 64x128 fp32 -> bf16 (2048 float4, 8/thread)
#pragma unroll
    for (int l = 0; l < 8; ++l) {
        int idx = t + l * 256;
        int o = idx >> 5, k4 = idx & 31;
        float4 w = *(const float4*)(W2 + (size_t)o * C1 + k4 * 4);
        u16x4 b; b.x = f2bf(w.x); b.y = f2bf(w.y); b.z = f2bf(w.z); b.w = f2bf(w.w);
        *(u16x4*)(Bs + o * 136 + k4 * 4) = b;
    }
    __syncthreads();
    int wave = t >> 6, lane = t & 63, quad = lane >> 4, mr = lane & 15;
    f32x4 acc[2][4];
#pragma unroll
    for (int i = 0; i < 2; i++)
#pragma unroll
        for (int j = 0; j < 4; j++)
#pragma unroll
            for (int r = 0; r < 4; r++) acc[i][j][r] = 0.f;
#pragma unroll
    for (int kc = 0; kc < 4; ++kc) {
        bf16x8 a0 = *(const bf16x8*)(As + (wave * 32 + mr) * 136 + kc * 32 + quad * 8);
        bf16x8 a1 = *(const bf16x8*)(As + (wave * 32 + 16 + mr) * 136 + kc * 32 + quad * 8);
#pragma unroll
        for (int nt = 0; nt < 4; ++nt) {
            bf16x8 b = *(const bf16x8*)(Bs + (nt * 16 + mr) * 136 + kc * 32 + quad * 8);
            acc[0][nt] = __builtin_amdgcn_mfma_f32_16x16x32_bf16(a0, b, acc[0][nt], 0, 0, 0);
            acc[1][nt] = __builtin_amdgcn_mfma_f32_16x16x32_bf16(a1, b, acc[1][nt], 0, 0, 0);
        }
    }
#pragma unroll
    for (int mf = 0; mf < 2; ++mf)
#pragma unroll
        for (int nt = 0; nt < 4; ++nt)
#pragma unroll
            for (int r = 0; r < 4; ++r) {
                int n = n0 + wave * 32 + mf * 16 + quad * 4 + r;
                if (n < N_NODES) ft2b[(size_t)n * D2 + nt * 16 + mr] = f2bf(acc[mf][nt][r]);
            }
}

// ---------------- el2/er2: one wave per node ----------------
__global__ void k_eler2(const u16* __restrict__ ft2b, const float* __restrict__ al2,
                        const float* __restrict__ ar2, float* __restrict__ el2,
                        float* __restrict__ er2) {
    int lane = threadIdx.x & 63;
    int n = blockIdx.x * 4 + (threadIdx.x >> 6);
    if (n >= N_NODES) return;
    float v = bf2f(ft2b[(size_t)n * D2 + lane]);
    float p = v * al2[lane];
    float q = v * ar2[lane];
#pragma unroll
    for (int off = 32; off > 0; off >>= 1) {
        p += __shfl_down(p, off, 64);
        q += __shfl_down(q, off, 64);
    }
    if (lane == 0) { el2[n] = p; er2[n] = q; }
}

// ---------------- layer1 aggregation: one wave per dst node ----------------
__global__ __launch_bounds__(256) void k_agg2(const u16* __restrict__ ft2b,
                                              const float* __restrict__ el2,
                                              const float* __restrict__ er2,
                                              const int* __restrict__ row_start,
                                              const int* __restrict__ csr_src,
                                              float* __restrict__ out2) {
    int lane = threadIdx.x & 63;
    int n = blockIdx.x * 4 + (threadIdx.x >> 6);
    if (n >= N_NODES) return;
    float ern = er2[n];
    int beg = row_start[n], end = row_start[n + 1];
    float acc = 0.f, ssum = 0.f;
    for (int i = beg; i < end; ++i) {
        int s = csr_src[i];
        float e = el2[s] + ern;
        e = e >= 0.f ? e : SLOPE * e;
        float w = __expf(e);
        acc = fmaf(w, bf2f(ft2b[(size_t)s * D2 + lane]), acc);
        ssum += w;
    }
    out2[(size_t)n * D2 + lane] = (ssum > 0.f) ? acc / ssum : 0.f;
}

extern "C" void kernel_launch(void* const* d_in, const int* in_sizes, int n_in,
                              void* d_out, int out_size, void* d_ws, size_t ws_size,
                              hipStream_t stream) {
    const float* feats = (const float*)d_in[0];
    const int* src = (const int*)d_in[1];
    const int* dst = (const int*)d_in[2];
    const float* W1 = (const float*)d_in[3];
    const float* al1 = (const float*)d_in[4];
    const float* ar1 = (const float*)d_in[5];
    const float* W2 = (const float*)d_in[6];
    const float* al2 = (const float*)d_in[7];
    const float* ar2 = (const float*)d_in[8];

    float* out0 = (float*)d_out;                       // feats copy [N,512]
    float* out1 = out0 + (size_t)N_NODES * D_IN;       // h1 [N,128]
    float* out2 = out1 + (size_t)N_NODES * C1;         // h  [N,64]

    char* ws = (char*)d_ws;
    size_t off = 0;
    auto alloc = [&](size_t bytes) -> void* {
        void* p = ws + off;
        off = (off + bytes + 255) & ~(size_t)255;
        return p;
    };
    u16* ft1b = (u16*)alloc((size_t)N_NODES * C1 * 2);
    u16* h1b = (u16*)alloc((size_t)N_NODES * C1 * 2);
    u16* ft2b = (u16*)alloc((size_t)N_NODES * D2 * 2);
    float* el1 = (float*)alloc((size_t)N_NODES * H1 * 4);
    float* er1 = (float*)alloc((size_t)N_NODES * H1 * 4);
    float* el2 = (float*)alloc((size_t)N_NODES * 4);
    float* er2 = (float*)alloc((size_t)N_NODES * 4);
    int* cnt = (int*)alloc((size_t)N_NODES * 4);
    int* row_start = (int*)alloc((size_t)(N_NODES + 1) * 4);
    int* cursor = (int*)alloc((size_t)N_NODES * 4);
    int* csr_src = (int*)alloc((size_t)N_EDGES * 4);
    int* partials = (int*)alloc((size_t)NB_SCAN * 4);
    int* offsets = (int*)alloc((size_t)NB_SCAN * 4);

    // CSR build (shared by both layers)
    hipMemsetAsync(cnt, 0, (size_t)N_NODES * 4, stream);
    k_hist<<<(N_EDGES + 255) / 256, 256, 0, stream>>>(dst, cnt);
    k_scan_partials<<<NB_SCAN, 256, 0, stream>>>(cnt, partials);
    k_scan_offsets<<<1, 1, 0, stream>>>(partials, offsets, row_start);
    k_scan_final<<<NB_SCAN, 256, 0, stream>>>(cnt, offsets, row_start, cursor);
    k_scatter<<<(N_EDGES + 255) / 256, 256, 0, stream>>>(src, dst, cursor, csr_src);

    // out0 = feats
    int n4 = N_NODES * D_IN / 4;
    k_copy_feats<<<(n4 + 255) / 256, 256, 0, stream>>>((const float4*)feats, (float4*)out0, n4);

    // layer 0
    k_gemm1<<<(N_NODES + 63) / 64, 256, 0, stream>>>(feats, W1, ft1b);
    k_eler1<<<(N_NODES * H1 + 255) / 256, 256, 0, stream>>>(ft1b, al1, ar1, el1, er1);
    k_agg1<<<(N_NODES + 3) / 4, 256, 0, stream>>>(ft1b, el1, er1, row_start, csr_src, out1, h1b);

    // layer 1
    k_gemm2<<<(N_NODES + 127) / 128, 256, 0, stream>>>(h1b, W2, ft2b);
    k_eler2<<<(N_NODES + 3) / 4, 256, 0, stream>>>(ft2b, al2, ar2, el2, er2);
    k_agg2<<<(N_NODES + 3) / 4, 256, 0, stream>>>(ft2b, el2, er2, row_start, csr_src, out2);
}

// Round 4
// 819.189 us; speedup vs baseline: 1.7461x; 1.2597x over previous
//
#include <hip/hip_runtime.h>
#include <math.h>

#define N_NODES 100000
#define N_EDGES 1600000
#define D_IN 512
#define C1 128   // H1*D1
#define H1 8
#define D2 64
#define SLOPE 0.2f
#define NB_SCAN 98   // ceil(100000/1024)

typedef unsigned short u16;
typedef unsigned int u32;
typedef u16 u16x4 __attribute__((ext_vector_type(4)));
typedef u16 u16x8 __attribute__((ext_vector_type(8)));
typedef short bf16x8 __attribute__((ext_vector_type(8)));
typedef float f32x4 __attribute__((ext_vector_type(4)));

__device__ __forceinline__ u16 f2bf(float f) {
    unsigned u = __builtin_bit_cast(unsigned, f);
    u += 0x7fffu + ((u >> 16) & 1u);   // RNE
    return (u16)(u >> 16);
}
__device__ __forceinline__ float bf2f(u16 v) {
    unsigned u = ((unsigned)v) << 16;
    return __builtin_bit_cast(float, u);
}
__device__ __forceinline__ float bflo(u32 u) { return __builtin_bit_cast(float, u << 16); }
__device__ __forceinline__ float bfhi(u32 u) { return __builtin_bit_cast(float, u & 0xffff0000u); }
__device__ __forceinline__ float lrelu(float e) { return e >= 0.f ? e : SLOPE * e; }

// ---------------- W1 -> bf16 (once; removes redundant per-block conversion in gemm1) ----
__global__ void k_prep_w1(const float* __restrict__ W1, u16* __restrict__ W1b) {
    int i = blockIdx.x * blockDim.x + threadIdx.x;   // one float4 each; 16384 total
    float4 v = ((const float4*)W1)[i];
    u16x4 b; b.x = f2bf(v.x); b.y = f2bf(v.y); b.z = f2bf(v.z); b.w = f2bf(v.w);
    ((u16x4*)W1b)[i] = b;
}

// ---------------- CSR build ----------------
__global__ void k_hist(const int* __restrict__ dst, int* __restrict__ cnt) {
    int e = blockIdx.x * blockDim.x + threadIdx.x;
    if (e < N_EDGES) atomicAdd(&cnt[dst[e]], 1);
}

__global__ void k_scan_partials(const int* __restrict__ cnt, int* __restrict__ partials) {
    __shared__ int s[256];
    int t = threadIdx.x;
    int base = blockIdx.x * 1024 + t * 4;
    int sum = 0;
#pragma unroll
    for (int j = 0; j < 4; j++) { int i = base + j; if (i < N_NODES) sum += cnt[i]; }
    s[t] = sum;
    __syncthreads();
    for (int off = 128; off > 0; off >>= 1) {
        if (t < off) s[t] += s[t + off];
        __syncthreads();
    }
    if (t == 0) partials[blockIdx.x] = s[0];
}

__global__ void k_scan_offsets(const int* __restrict__ partials, int* __restrict__ offsets,
                               int* __restrict__ row_start) {
    __shared__ int s[128];
    int t = threadIdx.x;
    int v = (t < NB_SCAN) ? partials[t] : 0;
    s[t] = v;
    __syncthreads();
    for (int off = 1; off < 128; off <<= 1) {
        int x = (t >= off) ? s[t - off] : 0;
        __syncthreads();
        s[t] += x;
        __syncthreads();
    }
    if (t < NB_SCAN) offsets[t] = s[t] - v;
    if (t == NB_SCAN - 1) row_start[N_NODES] = s[t];
}

__global__ void k_scan_final(const int* __restrict__ cnt, const int* __restrict__ offsets,
                             int* __restrict__ row_start, int* __restrict__ cursor) {
    __shared__ int s[256];
    int t = threadIdx.x;
    int base = blockIdx.x * 1024 + t * 4;
    int v[4];
    int sum = 0;
#pragma unroll
    for (int j = 0; j < 4; j++) {
        int i = base + j;
        v[j] = (i < N_NODES) ? cnt[i] : 0;
        sum += v[j];
    }
    s[t] = sum;
    __syncthreads();
    for (int off = 1; off < 256; off <<= 1) {
        int x = (t >= off) ? s[t - off] : 0;
        __syncthreads();
        s[t] += x;
        __syncthreads();
    }
    int b = offsets[blockIdx.x] + s[t] - sum;
    int e = 0;
#pragma unroll
    for (int j = 0; j < 4; j++) {
        int i = base + j;
        if (i < N_NODES) { row_start[i] = b + e; cursor[i] = b + e; }
        e += v[j];
    }
}

__global__ void k_scatter(const int* __restrict__ src, const int* __restrict__ dst,
                          int* __restrict__ cursor, int* __restrict__ csr_src) {
    int e = blockIdx.x * blockDim.x + threadIdx.x;
    if (e < N_EDGES) {
        int pos = atomicAdd(&cursor[dst[e]], 1);
        csr_src[pos] = src[e];
    }
}

// ---------------- GEMM1 (bf16 MFMA) + fused feats->out0 copy ----------------
// M_tile=64 (4 waves x 16 rows), N=128 (8 col-tiles of 16), BK=32
__global__ __launch_bounds__(256) void k_gemm1(const float* __restrict__ feats,
                                               const u16* __restrict__ W1b,
                                               u16* __restrict__ ft1b,
                                               float* __restrict__ out0) {
    __shared__ u16 As[64 * 40];    // [row][k] stride 40
    __shared__ u16 Bs[128 * 40];   // [o][k] stride 40
    int t = threadIdx.x;
    int m0 = blockIdx.x * 64;
    int wave = t >> 6, lane = t & 63, quad = lane >> 4, mr = lane & 15;

    f32x4 acc[8];
#pragma unroll
    for (int i = 0; i < 8; i++)
#pragma unroll
        for (int j = 0; j < 4; j++) acc[i][j] = 0.f;

    for (int kt = 0; kt < D_IN; kt += 32) {
        __syncthreads();
        // stage A: 64 rows x 32 k fp32 -> bf16 (512 float4, 2/thread); also write out0
#pragma unroll
        for (int l = 0; l < 2; ++l) {
            int idx = t + l * 256;
            int row = idx >> 3, k4 = idx & 7;
            int n = m0 + row;
            float4 v = make_float4(0.f, 0.f, 0.f, 0.f);
            if (n < N_NODES) {
                v = *(const float4*)(feats + (size_t)n * D_IN + kt + k4 * 4);
                *(float4*)(out0 + (size_t)n * D_IN + kt + k4 * 4) = v;
            }
            u16x4 b; b.x = f2bf(v.x); b.y = f2bf(v.y); b.z = f2bf(v.z); b.w = f2bf(v.w);
            *(u16x4*)(As + row * 40 + k4 * 4) = b;
        }
        // stage B: 128 rows x 32 k bf16 (512 u16x8, 2/thread)
#pragma unroll
        for (int l = 0; l < 2; ++l) {
            int idx = t + l * 256;
            int o = idx >> 2, k8 = idx & 3;
            *(u16x8*)(Bs + o * 40 + k8 * 8) = *(const u16x8*)(W1b + (size_t)o * D_IN + kt + k8 * 8);
        }
        __syncthreads();
        bf16x8 a = *(const bf16x8*)(As + (wave * 16 + mr) * 40 + quad * 8);
#pragma unroll
        for (int nt = 0; nt < 8; ++nt) {
            bf16x8 b = *(const bf16x8*)(Bs + (nt * 16 + mr) * 40 + quad * 8);
            acc[nt] = __builtin_amdgcn_mfma_f32_16x16x32_bf16(a, b, acc[nt], 0, 0, 0);
        }
    }
    // epilogue: C/D layout col=lane&15, row=quad*4+reg
#pragma unroll
    for (int nt = 0; nt < 8; ++nt)
#pragma unroll
        for (int r = 0; r < 4; ++r) {
            int n = m0 + wave * 16 + quad * 4 + r;
            if (n < N_NODES) ft1b[(size_t)n * C1 + nt * 16 + mr] = f2bf(acc[nt][r]);
        }
}

// ---------------- el1/er1 per (node, head) ----------------
__global__ void k_eler1(const u16* __restrict__ ft1b, const float* __restrict__ al1,
                        const float* __restrict__ ar1, float* __restrict__ el1,
                        float* __restrict__ er1) {
    int g = blockIdx.x * blockDim.x + threadIdx.x;
    if (g >= N_NODES * H1) return;
    int n = g >> 3, h = g & 7;
    const u16* f = ft1b + (size_t)n * C1 + h * 16;
    float sl = 0.f, sr = 0.f;
#pragma unroll
    for (int d = 0; d < 16; ++d) {
        float v = bf2f(f[d]);
        sl = fmaf(v, al1[h * 16 + d], sl);
        sr = fmaf(v, ar1[h * 16 + d], sr);
    }
    el1[g] = sl;
    er1[g] = sr;
}

// ---------------- layer0 aggregation: one wave per dst node, channel-pair lanes ---------
__global__ __launch_bounds__(256) void k_agg1(const u16* __restrict__ ft1b,
                                              const float* __restrict__ el1,
                                              const float* __restrict__ er1,
                                              const int* __restrict__ row_start,
                                              const int* __restrict__ csr_src,
                                              float* __restrict__ h1out,
                                              u32* __restrict__ h1b) {
    int lane = threadIdx.x & 63;
    int n = blockIdx.x * 4 + (threadIdx.x >> 6);
    if (n >= N_NODES) return;
    int h = lane >> 3;                  // head for channels 2*lane, 2*lane+1
    float era = er1[n * 8 + h];
    int beg = row_start[n], end = row_start[n + 1];
    float a0 = 0.f, a1 = 0.f, sw = 0.f;
    const u32* ftp = (const u32*)ft1b;  // row = 64 u32
    int i = beg;
    for (; i + 4 <= end; i += 4) {
        int s0 = csr_src[i + 0], s1 = csr_src[i + 1];
        int s2 = csr_src[i + 2], s3 = csr_src[i + 3];
        float e0 = el1[s0 * 8 + h], e1 = el1[s1 * 8 + h];
        float e2 = el1[s2 * 8 + h], e3 = el1[s3 * 8 + h];
        u32 f0 = ftp[s0 * 64 + lane], f1 = ftp[s1 * 64 + lane];
        u32 f2 = ftp[s2 * 64 + lane], f3 = ftp[s3 * 64 + lane];
        float w0 = __expf(lrelu(e0 + era));
        float w1 = __expf(lrelu(e1 + era));
        float w2 = __expf(lrelu(e2 + era));
        float w3 = __expf(lrelu(e3 + era));
        a0 = fmaf(w0, bflo(f0), a0); a1 = fmaf(w0, bfhi(f0), a1);
        a0 = fmaf(w1, bflo(f1), a0); a1 = fmaf(w1, bfhi(f1), a1);
        a0 = fmaf(w2, bflo(f2), a0); a1 = fmaf(w2, bfhi(f2), a1);
        a0 = fmaf(w3, bflo(f3), a0); a1 = fmaf(w3, bfhi(f3), a1);
        sw += w0 + w1 + w2 + w3;
    }
    for (; i < end; ++i) {
        int s = csr_src[i];
        float e = el1[s * 8 + h];
        u32 f = ftp[s * 64 + lane];
        float w = __expf(lrelu(e + era));
        a0 = fmaf(w, bflo(f), a0); a1 = fmaf(w, bfhi(f), a1);
        sw += w;
    }
    float r0 = (sw > 0.f) ? fmaxf(a0 / sw, 0.f) : 0.f;   // relu
    float r1 = (sw > 0.f) ? fmaxf(a1 / sw, 0.f) : 0.f;
    float2 rr; rr.x = r0; rr.y = r1;
    *(float2*)(h1out + (size_t)n * C1 + 2 * lane) = rr;
    h1b[n * 64 + lane] = (u32)f2bf(r0) | ((u32)f2bf(r1) << 16);
}

// ---------------- GEMM2 (bf16 MFMA): ft2b[n][o] = sum_k h1[n][k]*W2[o][k] ----------------
// 128 nodes/block, N=64 (4 col-tiles), K=128 staged once
__global__ __launch_bounds__(256) void k_gemm2(const u16* __restrict__ h1b,
                                               const float* __restrict__ W2,
                                               u16* __restrict__ ft2b) {
    __shared__ u16 As[128 * 136];
    __shared__ u16 Bs[64 * 136];
    int t = threadIdx.x;
    int n0 = blockIdx.x * 128;
    // stage A: 128 rows x 128 bf16 = 2048 x 16B chunks, 8/thread
#pragma unroll
    for (int l = 0; l < 8; ++l) {
        int idx = t + l * 256;
        int row = idx >> 4, c8 = idx & 15;
        int n = n0 + row;
        u16x8 v;
#pragma unroll
        for (int j = 0; j < 8; j++) v[j] = 0;
        if (n < N_NODES) v = *(const u16x8*)(h1b + (size_t)n * C1 + c8 * 8);
        *(u16x8*)(As + row * 136 + c8 * 8) = v;
    }
    // stage B: W2 64x128 fp32 -> bf16 (2048 float4, 8/thread)
#pragma unroll
    for (int l = 0; l < 8; ++l) {
        int idx = t + l * 256;
        int o = idx >> 5, k4 = idx & 31;
        float4 w = *(const float4*)(W2 + (size_t)o * C1 + k4 * 4);
        u16x4 b; b.x = f2bf(w.x); b.y = f2bf(w.y); b.z = f2bf(w.z); b.w = f2bf(w.w);
        *(u16x4*)(Bs + o * 136 + k4 * 4) = b;
    }
    __syncthreads();
    int wave = t >> 6, lane = t & 63, quad = lane >> 4, mr = lane & 15;
    f32x4 acc[2][4];
#pragma unroll
    for (int i = 0; i < 2; i++)
#pragma unroll
        for (int j = 0; j < 4; j++)
#pragma unroll
            for (int r = 0; r < 4; r++) acc[i][j][r] = 0.f;
#pragma unroll
    for (int kc = 0; kc < 4; ++kc) {
        bf16x8 a0 = *(const bf16x8*)(As + (wave * 32 + mr) * 136 + kc * 32 + quad * 8);
        bf16x8 a1 = *(const bf16x8*)(As + (wave * 32 + 16 + mr) * 136 + kc * 32 + quad * 8);
#pragma unroll
        for (int nt = 0; nt < 4; ++nt) {
            bf16x8 b = *(const bf16x8*)(Bs + (nt * 16 + mr) * 136 + kc * 32 + quad * 8);
            acc[0][nt] = __builtin_amdgcn_mfma_f32_16x16x32_bf16(a0, b, acc[0][nt], 0, 0, 0);
            acc[1][nt] = __builtin_amdgcn_mfma_f32_16x16x32_bf16(a1, b, acc[1][nt], 0, 0, 0);
        }
    }
#pragma unroll
    for (int mf = 0; mf < 2; ++mf)
#pragma unroll
        for (int nt = 0; nt < 4; ++nt)
#pragma unroll
            for (int r = 0; r < 4; ++r) {
                int n = n0 + wave * 32 + mf * 16 + quad * 4 + r;
                if (n < N_NODES) ft2b[(size_t)n * D2 + nt * 16 + mr] = f2bf(acc[mf][nt][r]);
            }
}

// ---------------- el2/er2: one wave per node ----------------
__global__ void k_eler2(const u16* __restrict__ ft2b, const float* __restrict__ al2,
                        const float* __restrict__ ar2, float* __restrict__ el2,
                        float* __restrict__ er2) {
    int lane = threadIdx.x & 63;
    int n = blockIdx.x * 4 + (threadIdx.x >> 6);
    if (n >= N_NODES) return;
    float v = bf2f(ft2b[(size_t)n * D2 + lane]);
    float p = v * al2[lane];
    float q = v * ar2[lane];
#pragma unroll
    for (int off = 32; off > 0; off >>= 1) {
        p += __shfl_down(p, off, 64);
        q += __shfl_down(q, off, 64);
    }
    if (lane == 0) { el2[n] = p; er2[n] = q; }
}

// ---------------- layer1 aggregation: half-wave per edge, 2 ch/lane --------------------
__global__ __launch_bounds__(256) void k_agg2(const u16* __restrict__ ft2b,
                                              const float* __restrict__ el2,
                                              const float* __restrict__ er2,
                                              const int* __restrict__ row_start,
                                              const int* __restrict__ csr_src,
                                              float* __restrict__ out2) {
    int lane = threadIdx.x & 63;
    int n = blockIdx.x * 4 + (threadIdx.x >> 6);
    if (n >= N_NODES) return;
    int half = lane >> 5;
    int c = (lane & 31) * 2;            // channel pair
    float ern = er2[n];
    int beg = row_start[n], end = row_start[n + 1];
    float a0 = 0.f, a1 = 0.f, sw = 0.f;
    const u32* ftp = (const u32*)ft2b;  // row = 32 u32
    int i = beg + half;
    for (; i + 2 < end; i += 4) {       // 2 edges per half per iter (4 per wave)
        int s0 = csr_src[i], s1 = csr_src[i + 2];
        float e0 = el2[s0], e1 = el2[s1];
        u32 f0 = ftp[s0 * 32 + (lane & 31)], f1 = ftp[s1 * 32 + (lane & 31)];
        float w0 = __expf(lrelu(e0 + ern));
        float w1 = __expf(lrelu(e1 + ern));
        a0 = fmaf(w0, bflo(f0), a0); a1 = fmaf(w0, bfhi(f0), a1);
        a0 = fmaf(w1, bflo(f1), a0); a1 = fmaf(w1, bfhi(f1), a1);
        sw += w0 + w1;
    }
    for (; i < end; i += 2) {
        int s = csr_src[i];
        float e = el2[s];
        u32 f = ftp[s * 32 + (lane & 31)];
        float w = __expf(lrelu(e + ern));
        a0 = fmaf(w, bflo(f), a0); a1 = fmaf(w, bfhi(f), a1);
        sw += w;
    }
    a0 += __shfl_xor(a0, 32, 64);
    a1 += __shfl_xor(a1, 32, 64);
    sw += __shfl_xor(sw, 32, 64);
    if (half == 0) {
        float2 rr;
        rr.x = (sw > 0.f) ? a0 / sw : 0.f;
        rr.y = (sw > 0.f) ? a1 / sw : 0.f;
        *(float2*)(out2 + (size_t)n * D2 + c) = rr;
    }
}

extern "C" void kernel_launch(void* const* d_in, const int* in_sizes, int n_in,
                              void* d_out, int out_size, void* d_ws, size_t ws_size,
                              hipStream_t stream) {
    const float* feats = (const float*)d_in[0];
    const int* src = (const int*)d_in[1];
    const int* dst = (const int*)d_in[2];
    const float* W1 = (const float*)d_in[3];
    const float* al1 = (const float*)d_in[4];
    const float* ar1 = (const float*)d_in[5];
    const float* W2 = (const float*)d_in[6];
    const float* al2 = (const float*)d_in[7];
    const float* ar2 = (const float*)d_in[8];

    float* out0 = (float*)d_out;                       // feats copy [N,512]
    float* out1 = out0 + (size_t)N_NODES * D_IN;       // h1 [N,128]
    float* out2 = out1 + (size_t)N_NODES * C1;         // h  [N,64]

    char* ws = (char*)d_ws;
    size_t off = 0;
    auto alloc = [&](size_t bytes) -> void* {
        void* p = ws + off;
        off = (off + bytes + 255) & ~(size_t)255;
        return p;
    };
    u16* ft1b = (u16*)alloc((size_t)N_NODES * C1 * 2);
    u16* h1b = (u16*)alloc((size_t)N_NODES * C1 * 2);
    u16* ft2b = (u16*)alloc((size_t)N_NODES * D2 * 2);
    u16* W1b = (u16*)alloc((size_t)C1 * D_IN * 2);
    float* el1 = (float*)alloc((size_t)N_NODES * H1 * 4);
    float* er1 = (float*)alloc((size_t)N_NODES * H1 * 4);
    float* el2 = (float*)alloc((size_t)N_NODES * 4);
    float* er2 = (float*)alloc((size_t)N_NODES * 4);
    int* cnt = (int*)alloc((size_t)N_NODES * 4);
    int* row_start = (int*)alloc((size_t)(N_NODES + 1) * 4);
    int* cursor = (int*)alloc((size_t)N_NODES * 4);
    int* csr_src = (int*)alloc((size_t)N_EDGES * 4);
    int* partials = (int*)alloc((size_t)NB_SCAN * 4);
    int* offsets = (int*)alloc((size_t)NB_SCAN * 4);

    // CSR build (shared by both layers)
    hipMemsetAsync(cnt, 0, (size_t)N_NODES * 4, stream);
    k_hist<<<(N_EDGES + 255) / 256, 256, 0, stream>>>(dst, cnt);
    k_scan_partials<<<NB_SCAN, 256, 0, stream>>>(cnt, partials);
    k_scan_offsets<<<1, 128, 0, stream>>>(partials, offsets, row_start);
    k_scan_final<<<NB_SCAN, 256, 0, stream>>>(cnt, offsets, row_start, cursor);
    k_scatter<<<(N_EDGES + 255) / 256, 256, 0, stream>>>(src, dst, cursor, csr_src);

    // weights prep
    k_prep_w1<<<64, 256, 0, stream>>>(W1, W1b);

    // layer 0 (gemm1 also writes out0 = feats)
    k_gemm1<<<(N_NODES + 63) / 64, 256, 0, stream>>>(feats, W1b, ft1b, out0);
    k_eler1<<<(N_NODES * H1 + 255) / 256, 256, 0, stream>>>(ft1b, al1, ar1, el1, er1);
    k_agg1<<<(N_NODES + 3) / 4, 256, 0, stream>>>(ft1b, el1, er1, row_start, csr_src, out1, (u32*)h1b);

    // layer 1
    k_gemm2<<<(N_NODES + 127) / 128, 256, 0, stream>>>(h1b, W2, ft2b);
    k_eler2<<<(N_NODES + 3) / 4, 256, 0, stream>>>(ft2b, al2, ar2, el2, er2);
    k_agg2<<<(N_NODES + 3) / 4, 256, 0, stream>>>(ft2b, el2, er2, row_start, csr_src, out2);
}